// Round 2
// baseline (19019.774 us; speedup 1.0000x reference)
//
#include <hip/hip_runtime.h>

// ---------------------------------------------------------------------------
// SubtasksRecurrence: T=128 sequential steps, B=256 independent rows.
// R2: hierarchical grid barrier (8 arrival lines + root + 8 release lines),
//     l/c folded into the two 256-streams (per-thread redundant softmax),
//     gating applied in phase B (hnT eliminated), unroll 16 on streams.
// All math f32 to keep categorical argmax decisions identical to reference.
// ---------------------------------------------------------------------------

#define RNG_PARTITIONABLE 1

#define T_STEPS 128
#define B_ROWS  256
#define H_DIM   256
#define N_DIM   16
#define S_DIM   32
#define TOT     338
#define CONV    4096
#define LDWF    4161   // W_f row stride (CONV + 2S + 1)
#define LDWB    4128   // W_beta row stride (CONV + S)

// ------------------------------- threefry ----------------------------------
__device__ __forceinline__ void tf2x32(unsigned k0, unsigned k1, unsigned c0, unsigned c1,
                                       unsigned &o0, unsigned &o1) {
  const unsigned ks2 = k0 ^ k1 ^ 0x1BD11BDAu;
  unsigned x0 = c0 + k0;
  unsigned x1 = c1 + k1;
#define TFR(r) { x0 += x1; x1 = (x1 << (r)) | (x1 >> (32 - (r))); x1 ^= x0; }
  TFR(13) TFR(15) TFR(26) TFR(6)
  x0 += k1; x1 += ks2 + 1u;
  TFR(17) TFR(29) TFR(16) TFR(24)
  x0 += ks2; x1 += k0 + 2u;
  TFR(13) TFR(15) TFR(26) TFR(6)
  x0 += k0; x1 += k1 + 3u;
  TFR(17) TFR(29) TFR(16) TFR(24)
  x0 += k1; x1 += ks2 + 4u;
  TFR(13) TFR(15) TFR(26) TFR(6)
  x0 += ks2; x1 += k0 + 5u;
#undef TFR
  o0 = x0; o1 = x1;
}

__device__ __forceinline__ void rng_key(unsigned j, unsigned &k0, unsigned &k1) {
#if RNG_PARTITIONABLE
  tf2x32(0u, 42u, 0u, j, k0, k1);
#else
  unsigned w[2];
  for (int q = 0; q < 2; ++q) {
    unsigned i = 2u*j + (unsigned)q, a, b;
    if (i < 256u) { tf2x32(0u, 42u, i, 256u + i, a, b); w[q] = a; }
    else          { tf2x32(0u, 42u, i - 256u, i, a, b); w[q] = b; }
  }
  k0 = w[0]; k1 = w[1];
#endif
}

__device__ __forceinline__ unsigned rng_bits(unsigned k0, unsigned k1, unsigned idx, unsigned total) {
#if RNG_PARTITIONABLE
  unsigned o0, o1;
  tf2x32(k0, k1, 0u, idx, o0, o1);
  return o0 ^ o1;
#else
  unsigned half = total >> 1, o0, o1;
  if (idx < half) { tf2x32(k0, k1, idx, half + idx, o0, o1); return o0; }
  else            { tf2x32(k0, k1, idx - half, idx, o0, o1); return o1; }
#endif
}

__device__ __forceinline__ float gumbel_from_bits(unsigned bits) {
  float u0 = __uint_as_float(0x3f800000u | (bits >> 9)) - 1.0f;
  float u  = fmaxf(u0, 1.17549435e-38f);
  return -logf(-logf(u));
}

// ------------------------------ small kernels ------------------------------
__global__ __launch_bounds__(256) void rng_k(float* __restrict__ ggum, float* __restrict__ bgum) {
  unsigned tid = blockIdx.x * 256u + threadIdx.x;
  const unsigned NG = T_STEPS * B_ROWS * N_DIM;
  const unsigned NB = T_STEPS * B_ROWS * 2;
  if (tid < NG) {
    unsigned t = tid / (B_ROWS * N_DIM);
    unsigned i = tid % (B_ROWS * N_DIM);
    unsigned k0, k1; rng_key(2u * t, k0, k1);
    ggum[tid] = gumbel_from_bits(rng_bits(k0, k1, i, B_ROWS * N_DIM));
  } else if (tid < NG + NB) {
    unsigned q = tid - NG;
    unsigned t = q / (B_ROWS * 2);
    unsigned i = q % (B_ROWS * 2);
    unsigned k0, k1; rng_key(2u * t + 1u, k0, k1);
    bgum[q] = gumbel_from_bits(rng_bits(k0, k1, i, B_ROWS * 2));
  }
}

__global__ __launch_bounds__(256) void prep_k(const float* __restrict__ W_pi, float* __restrict__ wpiT) {
  int tid = blockIdx.x * 256 + threadIdx.x;
  if (tid < 288 * 16) {
    int k = tid / 16, o = tid % 16;
    wpiT[k * 16 + o] = W_pi[o * 288 + k];
  }
}

__global__ __launch_bounds__(256) void init_k(const float* __restrict__ hx0,
                                              float* __restrict__ hT0, float* __restrict__ rT,
                                              float* __restrict__ gT, float* __restrict__ brow) {
  int tid = blockIdx.x * 256 + threadIdx.x;
  if (tid < 65536) {
    int k = tid >> 8, b = tid & 255;
    hT0[k * 256 + b] = hx0[b * TOT + 48 + k];
  } else if (tid < 65536 + 8192) {
    int q = tid - 65536; int j = q >> 8, b = q & 255;
    rT[j * 256 + b] = hx0[b * TOT + 16 + j];
  } else if (tid < 65536 + 16384) {
    int q = tid - 65536 - 8192; int j = q >> 8, b = q & 255;
    gT[j * 256 + b] = hx0[b * TOT + 304 + j];
  } else if (tid < 65536 + 16384 + 256) {
    int b = tid - 65536 - 16384;
    brow[b] = hx0[b * TOT + 336];
  }
}

__device__ __forceinline__ float waveRed(float v) {
  v += __shfl_down(v, 32, 64);
  v += __shfl_down(v, 16, 64);
  v += __shfl_down(v, 8, 64);
  v += __shfl_down(v, 4, 64);
  v += __shfl_down(v, 2, 64);
  v += __shfl_down(v, 1, 64);
  return v;
}

__global__ __launch_bounds__(256) void bx_k(const float* __restrict__ obs,
                                            const float* __restrict__ W_beta,
                                            const float* __restrict__ b_beta,
                                            float* __restrict__ bxv) {
  int m = blockIdx.x, tid = threadIdx.x;
  const float* row = obs + (size_t)m * CONV;
  float p0 = 0.f, p1 = 0.f;
  for (int i = tid; i < CONV; i += 256) {
    float o = row[i];
    p0 = fmaf(o, W_beta[i], p0);
    p1 = fmaf(o, W_beta[LDWB + i], p1);
  }
  p0 = waveRed(p0); p1 = waveRed(p1);
  __shared__ float sc[2][4];
  int w = tid >> 6;
  if ((tid & 63) == 0) { sc[0][w] = p0; sc[1][w] = p1; }
  __syncthreads();
  if (tid == 0) bxv[(size_t)m * 2 + 0] = sc[0][0] + sc[0][1] + sc[0][2] + sc[0][3] + b_beta[0];
  if (tid == 1) bxv[(size_t)m * 2 + 1] = sc[1][0] + sc[1][1] + sc[1][2] + sc[1][3] + b_beta[1];
}

// ------------------------------- big GEMM ----------------------------------
struct __attribute__((packed, aligned(4))) F4 { float x, y, z, w; };

__global__ __launch_bounds__(256) void gemm1_k(const float* __restrict__ A,
                                               const float* __restrict__ W,
                                               const float* __restrict__ bias,
                                               float* __restrict__ C1T) {
  __shared__ __align__(16) float As[32][68];
  __shared__ __align__(16) float Bs[32][68];
  int bid = blockIdx.x;
  int mt = bid & 511, nt = bid >> 9;
  int m0 = mt * 64, n0 = nt * 64;
  int tid = threadIdx.x;
  int tm = tid & 15, tn = tid >> 4;
  int lr = tid >> 2;
  int lc = (tid & 3) * 8;
  float acc[4][4] = {};
  for (int k0 = 0; k0 < CONV; k0 += 32) {
    F4 a0 = *(const F4*)(A + (size_t)(m0 + lr) * CONV + k0 + lc);
    F4 a1 = *(const F4*)(A + (size_t)(m0 + lr) * CONV + k0 + lc + 4);
    F4 b0 = *(const F4*)(W + (size_t)(n0 + lr) * LDWF + k0 + lc);
    F4 b1 = *(const F4*)(W + (size_t)(n0 + lr) * LDWF + k0 + lc + 4);
    __syncthreads();
    As[lc + 0][lr] = a0.x; As[lc + 1][lr] = a0.y; As[lc + 2][lr] = a0.z; As[lc + 3][lr] = a0.w;
    As[lc + 4][lr] = a1.x; As[lc + 5][lr] = a1.y; As[lc + 6][lr] = a1.z; As[lc + 7][lr] = a1.w;
    Bs[lc + 0][lr] = b0.x; Bs[lc + 1][lr] = b0.y; Bs[lc + 2][lr] = b0.z; Bs[lc + 3][lr] = b0.w;
    Bs[lc + 4][lr] = b1.x; Bs[lc + 5][lr] = b1.y; Bs[lc + 6][lr] = b1.z; Bs[lc + 7][lr] = b1.w;
    __syncthreads();
#pragma unroll
    for (int kk = 0; kk < 32; ++kk) {
      const float4 av = *(const float4*)&As[kk][tm * 4];
      const float4 bv = *(const float4*)&Bs[kk][tn * 4];
      acc[0][0] = fmaf(av.x, bv.x, acc[0][0]); acc[0][1] = fmaf(av.x, bv.y, acc[0][1]);
      acc[0][2] = fmaf(av.x, bv.z, acc[0][2]); acc[0][3] = fmaf(av.x, bv.w, acc[0][3]);
      acc[1][0] = fmaf(av.y, bv.x, acc[1][0]); acc[1][1] = fmaf(av.y, bv.y, acc[1][1]);
      acc[1][2] = fmaf(av.y, bv.z, acc[1][2]); acc[1][3] = fmaf(av.y, bv.w, acc[1][3]);
      acc[2][0] = fmaf(av.z, bv.x, acc[2][0]); acc[2][1] = fmaf(av.z, bv.y, acc[2][1]);
      acc[2][2] = fmaf(av.z, bv.z, acc[2][2]); acc[2][3] = fmaf(av.z, bv.w, acc[2][3]);
      acc[3][0] = fmaf(av.w, bv.x, acc[3][0]); acc[3][1] = fmaf(av.w, bv.y, acc[3][1]);
      acc[3][2] = fmaf(av.w, bv.z, acc[3][2]); acc[3][3] = fmaf(av.w, bv.w, acc[3][3]);
    }
  }
  const int t = m0 >> 8;
  const int bb0 = (m0 & 255) + tm * 4;
  const int nn0 = n0 + tn * 4;
  float* cbase = C1T + (size_t)t * 65536;
#pragma unroll
  for (int j = 0; j < 4; ++j) {
    float bv = bias[nn0 + j];
#pragma unroll
    for (int i = 0; i < 4; ++i)
      cbase[(nn0 + j) * 256 + bb0 + i] = acc[i][j] + bv;
  }
}

// ------------------------------ grid barrier -------------------------------
// Hierarchical, monotonic. Layout in `bar` (unsigned words, 256B-spaced lines):
//   cnt[g]  at bar + g*64        (g = blockIdx.x & 7, 32 blocks/group)
//   root    at bar + 8*64
//   rel[g]  at bar + (16+g)*64
__device__ __forceinline__ void gsync(unsigned* bar, int idx1) {
  __syncthreads();
  if (threadIdx.x == 0) {
    const int g = (int)(blockIdx.x & 7u);
    unsigned* cnt  = bar + g * 64;
    unsigned* root = bar + 8 * 64;
    unsigned* rel  = bar + (16 + g) * 64;
    unsigned a = __hip_atomic_fetch_add(cnt, 1u, __ATOMIC_ACQ_REL, __HIP_MEMORY_SCOPE_AGENT);
    if (a == 32u * (unsigned)idx1 - 1u) {
      unsigned r = __hip_atomic_fetch_add(root, 1u, __ATOMIC_ACQ_REL, __HIP_MEMORY_SCOPE_AGENT);
      if (r == 8u * (unsigned)idx1 - 1u) {
#pragma unroll
        for (int j = 0; j < 8; ++j)
          __hip_atomic_store(bar + (16 + j) * 64, (unsigned)idx1, __ATOMIC_RELEASE, __HIP_MEMORY_SCOPE_AGENT);
      }
    }
    while (__hip_atomic_load(rel, __ATOMIC_ACQUIRE, __HIP_MEMORY_SCOPE_AGENT) < (unsigned)idx1)
      __builtin_amdgcn_s_sleep(2);
  }
  __syncthreads();
}

// ------------------------------ sequential ---------------------------------
__global__ __launch_bounds__(256, 1) void seq_k(
    const float* __restrict__ hx0, const float* __restrict__ task,
    const float* __restrict__ W_f, const float* __restrict__ W_ih,
    const float* __restrict__ W_hh, const float* __restrict__ b_ih,
    const float* __restrict__ b_hh, const float* __restrict__ W_u,
    const float* __restrict__ b_u, const float* __restrict__ W_s,
    const float* __restrict__ b_s, const float* __restrict__ b_pi,
    const float* __restrict__ W_beta, const float* __restrict__ C1T,
    const float* __restrict__ bxv, const float* __restrict__ wpiT,
    const float* __restrict__ ggum, const float* __restrict__ bgum,
    float* __restrict__ hT, float* __restrict__ sT,
    float* __restrict__ rT, float* __restrict__ gT, float* __restrict__ brow,
    unsigned* __restrict__ bar, float* __restrict__ out) {
  const int b = blockIdx.x;   // owns output row b AND GRU column triple {b, b+256, b+512}
  const int tid = threadIdx.x;

  __shared__ float l_sh[3];
  __shared__ float c_sh;
  __shared__ float p_sh[16], pn_sh[16], r_sh[32], rn_sh[32], g_sh[32];
  __shared__ float hrow_sh[256];
  __shared__ float logit_sh[16];
  __shared__ float red16[4][16];
  __shared__ int gidx_sh;
  __shared__ float misc_sh[4];  // 0: lp_g, 1: b', 2: lp_total

  if (tid < 16) p_sh[tid] = hx0[b * TOT + tid];
  if (tid < 32) {
    r_sh[tid] = hx0[b * TOT + 16 + tid];
    g_sh[tid] = hx0[b * TOT + 304 + tid];
  }
  __syncthreads();

  int cur = 0;
  for (int t = 0; t < T_STEPS; ++t) {
    const float* hTc = hT + (size_t)cur * 65536;
    float* hTn = hT + (size_t)(cur ^ 1) * 65536;

    // ---------------- Phase A ----------------
    // s column b: xpart + r/g/b parts (reads prev-step rT/gT/brow)
    {
      float sacc = C1T[(size_t)t * 65536 + b * 256 + tid];
      const float* wfr = W_f + (size_t)b * LDWF + CONV;
#pragma unroll
      for (int j = 0; j < 32; ++j) sacc = fmaf(rT[j * 256 + tid], wfr[j], sacc);
#pragma unroll
      for (int j = 0; j < 32; ++j) sacc = fmaf(gT[j * 256 + tid], wfr[32 + j], sacc);
      sacc = fmaf(brow[tid], wfr[64], sacc);
      sT[b * 256 + tid] = sacc;
    }
    // unified hT stream: gh triple (col b*) + l logits + c h-part (row tid)
    float gh0, gh1, gh2, chh;
    {
      const float* wh0 = W_hh + (size_t)b * 256;
      const float* wh1 = W_hh + (size_t)(b + 256) * 256;
      const float* wh2 = W_hh + (size_t)(b + 512) * 256;
      const float* wuh = W_u + 256;
      float g0 = 0.f, g1 = 0.f, g2 = 0.f, s0 = 0.f, s1 = 0.f, s2 = 0.f, ch = 0.f;
#pragma unroll 16
      for (int k = 0; k < 256; ++k) {
        float hv = hTc[k * 256 + tid];
        g0 = fmaf(hv, wh0[k], g0);
        g1 = fmaf(hv, wh1[k], g1);
        g2 = fmaf(hv, wh2[k], g2);
        s0 = fmaf(hv, W_s[k], s0);
        s1 = fmaf(hv, W_s[256 + k], s1);
        s2 = fmaf(hv, W_s[512 + k], s2);
        ch = fmaf(hv, wuh[k], ch);
      }
      gh0 = g0 + b_hh[b]; gh1 = g1 + b_hh[b + 256]; gh2 = g2 + b_hh[b + 512];
      chh = ch;
      s0 += b_s[0]; s1 += b_s[1]; s2 += b_s[2];
      float m = fmaxf(s0, fmaxf(s1, s2));
      float e0 = expf(s0 - m), e1 = expf(s1 - m), e2 = expf(s2 - m);
      float es = e0 + e1 + e2;
      // thread tid holds l for row tid; row-owner stash:
      if (tid == b) { l_sh[0] = e0 / es; l_sh[1] = e1 / es; l_sh[2] = e2 / es; }
    }
    __syncthreads();
    if (tid < 16) {
      float pm1 = (tid > 0) ? p_sh[tid - 1] : 0.f;
      float pp1 = (tid < 15) ? p_sh[tid + 1] : 0.f;
      pn_sh[tid] = l_sh[0] * pm1 + l_sh[1] * p_sh[tid] + l_sh[2] * pp1;
    }
    __syncthreads();
    if (tid < 32) {
      float acc = 0.f;
      const float* mrow = task + (size_t)b * 512 + tid;
#pragma unroll
      for (int n2 = 0; n2 < 16; ++n2) acc = fmaf(pn_sh[n2], mrow[n2 * 32], acc);
      rn_sh[tid] = acc;
    }
    gsync(bar, 3 * t + 1);

    // ---------------- Phase B ----------------
    // sT stream: gi triple + c s-part; then c, GRU, gated h' write.
    {
      const float* wi0 = W_ih + (size_t)b * 256;
      const float* wi1 = W_ih + (size_t)(b + 256) * 256;
      const float* wi2 = W_ih + (size_t)(b + 512) * 256;
      float i0 = 0.f, i1 = 0.f, i2 = 0.f, cs = 0.f;
#pragma unroll 16
      for (int k = 0; k < 256; ++k) {
        float sv = sT[k * 256 + tid];
        i0 = fmaf(sv, wi0[k], i0);
        i1 = fmaf(sv, wi1[k], i1);
        i2 = fmaf(sv, wi2[k], i2);
        cs = fmaf(sv, W_u[k], cs);
      }
      i0 += b_ih[b]; i1 += b_ih[b + 256]; i2 += b_ih[b + 512];
      float c = 1.0f / (1.0f + expf(-(cs + chh + b_u[0])));
      float rr = 1.0f / (1.0f + expf(-(i0 + gh0)));
      float zz = 1.0f / (1.0f + expf(-(i1 + gh1)));
      float nn2 = tanhf(i2 + rr * gh2);
      float ho = hTc[b * 256 + tid];
      float hnew = (1.0f - zz) * nn2 + zz * ho;
      hTn[b * 256 + tid] = c * hnew + (1.0f - c) * ho;   // gated h' directly
      if (tid == b) c_sh = c;
    }
    gsync(bar, 3 * t + 2);

    // ---------------- Phase C (row-owner) ----------------
    const float c = c_sh;
    const float omc = 1.0f - c;
    float hg = hTn[tid * 256 + b];   // issue scatter read early
    if (tid < 16) p_sh[tid] = c * pn_sh[tid] + omc * p_sh[tid];
    if (tid < 32) {
      float rv = c * rn_sh[tid] + omc * r_sh[tid];
      r_sh[tid] = rv;
      rT[tid * 256 + b] = rv;
    }
    hrow_sh[tid] = hg;
    __syncthreads();
    // logits_g = [h', r'] @ W_pi^T + b_pi
    {
      float part[16];
      const float* wrow = wpiT + tid * 16;
#pragma unroll
      for (int o = 0; o < 16; ++o) part[o] = hg * wrow[o];
      if (tid < 32) {
        const float* wrow2 = wpiT + (256 + tid) * 16;
        float rv = r_sh[tid];
#pragma unroll
        for (int o = 0; o < 16; ++o) part[o] = fmaf(rv, wrow2[o], part[o]);
      }
#pragma unroll
      for (int o = 0; o < 16; ++o) part[o] = waveRed(part[o]);
      int w = tid >> 6;
      if ((tid & 63) == 0) {
#pragma unroll
        for (int o = 0; o < 16; ++o) red16[w][o] = part[o];
      }
    }
    __syncthreads();
    if (tid < 16)
      logit_sh[tid] = red16[0][tid] + red16[1][tid] + red16[2][tid] + red16[3][tid] + b_pi[tid];
    __syncthreads();
    if (tid == 0) {
      const float* gg = ggum + ((size_t)t * 256 + b) * 16;
      float best = -3.402823466e+38f; int gidx = 0;
      for (int n2 = 0; n2 < 16; ++n2) {
        float v = logit_sh[n2] + gg[n2];
        if (v > best) { best = v; gidx = n2; }
      }
      float mx = logit_sh[0];
      for (int n2 = 1; n2 < 16; ++n2) mx = fmaxf(mx, logit_sh[n2]);
      float se = 0.f;
      for (int n2 = 0; n2 < 16; ++n2) se += expf(logit_sh[n2] - mx);
      misc_sh[0] = logit_sh[gidx] - mx - logf(se);
      gidx_sh = gidx;
    }
    __syncthreads();
    if (tid < 32) {
      float gv = c * task[(size_t)b * 512 + gidx_sh * 32 + tid] + omc * g_sh[tid];
      g_sh[tid] = gv;
      gT[tid * 256 + b] = gv;
    }
    __syncthreads();
    if (tid == 0) {
      const float* bx2 = bxv + ((size_t)t * 256 + b) * 2;
      float lb0 = bx2[0], lb1 = bx2[1];
      for (int s2 = 0; s2 < 32; ++s2) {
        float gv = g_sh[s2];
        lb0 = fmaf(gv, W_beta[CONV + s2], lb0);
        lb1 = fmaf(gv, W_beta[LDWB + CONV + s2], lb1);
      }
      const float* bg = bgum + ((size_t)t * 256 + b) * 2;
      int bidx = ((lb1 + bg[1]) > (lb0 + bg[0])) ? 1 : 0;
      float mb = fmaxf(lb0, lb1);
      float seb = expf(lb0 - mb) + expf(lb1 - mb);
      float lpb = (bidx ? lb1 : lb0) - mb - logf(seb);
      misc_sh[1] = (float)bidx;
      misc_sh[2] = misc_sh[0] + lpb;
      brow[b] = (float)bidx;
    }
    __syncthreads();
    // outputs: [p16, r32, h256, g32, b1, lp1]
    {
      size_t base = ((size_t)t * 256 + b) * TOT;
      float v;
      if (tid < 16) v = p_sh[tid];
      else if (tid < 48) v = r_sh[tid - 16];
      else v = hrow_sh[tid - 48];
      out[base + tid] = v;
      int s2 = tid + 256;
      if (s2 < TOT) {
        float v2;
        if (s2 < 304) v2 = hrow_sh[s2 - 48];
        else if (s2 < 336) v2 = g_sh[s2 - 304];
        else if (s2 == 336) v2 = misc_sh[1];
        else v2 = misc_sh[2];
        out[base + s2] = v2;
      }
    }
    gsync(bar, 3 * t + 3);
    cur ^= 1;
  }
}

// ------------------------------ host launch --------------------------------
extern "C" void kernel_launch(void* const* d_in, const int* in_sizes, int n_in,
                              void* d_out, int out_size, void* d_ws, size_t ws_size,
                              hipStream_t stream) {
  const float* obs    = (const float*)d_in[0];
  const float* task   = (const float*)d_in[1];
  const float* hx0    = (const float*)d_in[2];
  const float* W_ih   = (const float*)d_in[3];
  const float* W_hh   = (const float*)d_in[4];
  const float* b_ih   = (const float*)d_in[5];
  const float* b_hh   = (const float*)d_in[6];
  const float* W_f    = (const float*)d_in[7];
  const float* b_f    = (const float*)d_in[8];
  const float* W_u    = (const float*)d_in[9];
  const float* b_u    = (const float*)d_in[10];
  const float* W_s    = (const float*)d_in[11];
  const float* b_s    = (const float*)d_in[12];
  const float* W_pi   = (const float*)d_in[13];
  const float* b_pi   = (const float*)d_in[14];
  const float* W_beta = (const float*)d_in[15];
  const float* b_beta = (const float*)d_in[16];

  char* ws = (char*)d_ws;
  size_t off = 0;
  auto take = [&](size_t bytes) {
    size_t r = off;
    off += (bytes + 255) & ~(size_t)255;
    return r;
  };
  size_t off_bar  = take(8192);
  size_t off_wpiT = take((size_t)288 * 16 * 4);
  size_t off_ggum = take((size_t)T_STEPS * B_ROWS * N_DIM * 4);
  size_t off_bgum = take((size_t)T_STEPS * B_ROWS * 2 * 4);
  size_t off_hT   = take((size_t)2 * 65536 * 4);
  size_t off_sT   = take((size_t)65536 * 4);
  size_t off_rT   = take((size_t)8192 * 4);
  size_t off_gT   = take((size_t)8192 * 4);
  size_t off_brow = take((size_t)256 * 4);
  size_t off_bx   = take((size_t)T_STEPS * B_ROWS * 2 * 4);
  size_t off_C1T  = take((size_t)T_STEPS * B_ROWS * 256 * 4);
  if (off > ws_size) return;

  unsigned* bar  = (unsigned*)(ws + off_bar);
  float* wpiT    = (float*)(ws + off_wpiT);
  float* ggum    = (float*)(ws + off_ggum);
  float* bgum    = (float*)(ws + off_bgum);
  float* hT      = (float*)(ws + off_hT);
  float* sT      = (float*)(ws + off_sT);
  float* rT      = (float*)(ws + off_rT);
  float* gT      = (float*)(ws + off_gT);
  float* brow    = (float*)(ws + off_brow);
  float* bxv     = (float*)(ws + off_bx);
  float* C1T     = (float*)(ws + off_C1T);

  hipMemsetAsync(ws + off_bar, 0, 8192, stream);
  hipLaunchKernelGGL(prep_k, dim3(18), dim3(256), 0, stream, W_pi, wpiT);
  hipLaunchKernelGGL(rng_k, dim3(2304), dim3(256), 0, stream, ggum, bgum);
  hipLaunchKernelGGL(init_k, dim3(321), dim3(256), 0, stream, hx0, hT, rT, gT, brow);
  hipLaunchKernelGGL(gemm1_k, dim3(2048), dim3(256), 0, stream, obs, W_f, b_f, C1T);
  hipLaunchKernelGGL(bx_k, dim3(32768), dim3(256), 0, stream, obs, W_beta, b_beta, bxv);
  hipLaunchKernelGGL(seq_k, dim3(256), dim3(256), 0, stream,
                     hx0, task, W_f, W_ih, W_hh, b_ih, b_hh, W_u, b_u, W_s, b_s, b_pi,
                     W_beta, C1T, bxv, wpiT, ggum, bgum,
                     hT, sT, rT, gT, brow, bar, (float*)d_out);
}

// Round 3
// 3864.391 us; speedup vs baseline: 4.9218x; 4.9218x over previous
//
#include <hip/hip_runtime.h>

// ---------------------------------------------------------------------------
// SubtasksRecurrence: T=128 sequential steps, B=256 independent rows.
// R3: KEY INSIGHT — the recurrence is fully batch-parallel (no cross-row
//     coupling anywhere). Block b owns batch row b end-to-end; h/s/p/r/g/M
//     live in LDS; gh/gi are 256-long streamed matvecs over transposed
//     weights (coalesced, L2-resident). ZERO grid synchronization.
// All math f32; accumulation orders kept from R1 (which passed) for all
// quantities feeding categorical argmax decisions.
// ---------------------------------------------------------------------------

#define RNG_PARTITIONABLE 1

#define T_STEPS 128
#define B_ROWS  256
#define TOT     338
#define CONV    4096
#define LDWF    4161   // W_f row stride (CONV + 2S + 1)
#define LDWB    4128   // W_beta row stride (CONV + S)

// ------------------------------- threefry ----------------------------------
__device__ __forceinline__ void tf2x32(unsigned k0, unsigned k1, unsigned c0, unsigned c1,
                                       unsigned &o0, unsigned &o1) {
  const unsigned ks2 = k0 ^ k1 ^ 0x1BD11BDAu;
  unsigned x0 = c0 + k0;
  unsigned x1 = c1 + k1;
#define TFR(r) { x0 += x1; x1 = (x1 << (r)) | (x1 >> (32 - (r))); x1 ^= x0; }
  TFR(13) TFR(15) TFR(26) TFR(6)
  x0 += k1; x1 += ks2 + 1u;
  TFR(17) TFR(29) TFR(16) TFR(24)
  x0 += ks2; x1 += k0 + 2u;
  TFR(13) TFR(15) TFR(26) TFR(6)
  x0 += k0; x1 += k1 + 3u;
  TFR(17) TFR(29) TFR(16) TFR(24)
  x0 += k1; x1 += ks2 + 4u;
  TFR(13) TFR(15) TFR(26) TFR(6)
  x0 += ks2; x1 += k0 + 5u;
#undef TFR
  o0 = x0; o1 = x1;
}

__device__ __forceinline__ void rng_key(unsigned j, unsigned &k0, unsigned &k1) {
#if RNG_PARTITIONABLE
  tf2x32(0u, 42u, 0u, j, k0, k1);
#else
  unsigned w[2];
  for (int q = 0; q < 2; ++q) {
    unsigned i = 2u*j + (unsigned)q, a, b;
    if (i < 256u) { tf2x32(0u, 42u, i, 256u + i, a, b); w[q] = a; }
    else          { tf2x32(0u, 42u, i - 256u, i, a, b); w[q] = b; }
  }
  k0 = w[0]; k1 = w[1];
#endif
}

__device__ __forceinline__ unsigned rng_bits(unsigned k0, unsigned k1, unsigned idx, unsigned total) {
#if RNG_PARTITIONABLE
  unsigned o0, o1;
  tf2x32(k0, k1, 0u, idx, o0, o1);
  return o0 ^ o1;
#else
  unsigned half = total >> 1, o0, o1;
  if (idx < half) { tf2x32(k0, k1, idx, half + idx, o0, o1); return o0; }
  else            { tf2x32(k0, k1, idx - half, idx, o0, o1); return o1; }
#endif
}

__device__ __forceinline__ float gumbel_from_bits(unsigned bits) {
  float u0 = __uint_as_float(0x3f800000u | (bits >> 9)) - 1.0f;
  float u  = fmaxf(u0, 1.17549435e-38f);
  return -logf(-logf(u));
}

// ------------------------------ small kernels ------------------------------
__global__ __launch_bounds__(256) void rng_k(float* __restrict__ ggum, float* __restrict__ bgum) {
  unsigned tid = blockIdx.x * 256u + threadIdx.x;
  const unsigned NG = T_STEPS * B_ROWS * 16;
  const unsigned NB = T_STEPS * B_ROWS * 2;
  if (tid < NG) {
    unsigned t = tid / (B_ROWS * 16);
    unsigned i = tid % (B_ROWS * 16);
    unsigned k0, k1; rng_key(2u * t, k0, k1);
    ggum[tid] = gumbel_from_bits(rng_bits(k0, k1, i, B_ROWS * 16));
  } else if (tid < NG + NB) {
    unsigned q = tid - NG;
    unsigned t = q / (B_ROWS * 2);
    unsigned i = q % (B_ROWS * 2);
    unsigned k0, k1; rng_key(2u * t + 1u, k0, k1);
    bgum[q] = gumbel_from_bits(rng_bits(k0, k1, i, B_ROWS * 2));
  }
}

// transposes: WihT/WhhT [k][part*256+o] <- W[(part*256+o)][k]; WfT [j][o] tail; wpiT [288][16]
__global__ __launch_bounds__(256) void prep_k(const float* __restrict__ W_ih,
                                              const float* __restrict__ W_hh,
                                              const float* __restrict__ W_f,
                                              const float* __restrict__ W_pi,
                                              float* __restrict__ WihT, float* __restrict__ WhhT,
                                              float* __restrict__ WfT, float* __restrict__ wpiT) {
  int tid = blockIdx.x * 256 + threadIdx.x;
  const int NW = 768 * 256;
  if (tid < NW) {
    int k = tid / 768, rem = tid % 768;
    WihT[tid] = W_ih[rem * 256 + k];
    WhhT[tid] = W_hh[rem * 256 + k];
  } else if (tid < NW + 65 * 256) {
    int q = tid - NW; int j = q >> 8, o = q & 255;
    WfT[q] = W_f[(size_t)o * LDWF + CONV + j];
  } else if (tid < NW + 65 * 256 + 288 * 16) {
    int q = tid - NW - 65 * 256; int kk = q / 16, o = q % 16;
    wpiT[q] = W_pi[o * 288 + kk];
  }
}

__device__ __forceinline__ float waveRed(float v) {
  v += __shfl_down(v, 32, 64);
  v += __shfl_down(v, 16, 64);
  v += __shfl_down(v, 8, 64);
  v += __shfl_down(v, 4, 64);
  v += __shfl_down(v, 2, 64);
  v += __shfl_down(v, 1, 64);
  return v;
}

__global__ __launch_bounds__(256) void bx_k(const float* __restrict__ obs,
                                            const float* __restrict__ W_beta,
                                            const float* __restrict__ b_beta,
                                            float* __restrict__ bxv) {
  int m = blockIdx.x, tid = threadIdx.x;
  const float* row = obs + (size_t)m * CONV;
  float p0 = 0.f, p1 = 0.f;
  for (int i = tid; i < CONV; i += 256) {
    float o = row[i];
    p0 = fmaf(o, W_beta[i], p0);
    p1 = fmaf(o, W_beta[LDWB + i], p1);
  }
  p0 = waveRed(p0); p1 = waveRed(p1);
  __shared__ float sc[2][4];
  int w = tid >> 6;
  if ((tid & 63) == 0) { sc[0][w] = p0; sc[1][w] = p1; }
  __syncthreads();
  if (tid == 0) bxv[(size_t)m * 2 + 0] = sc[0][0] + sc[0][1] + sc[0][2] + sc[0][3] + b_beta[0];
  if (tid == 1) bxv[(size_t)m * 2 + 1] = sc[1][0] + sc[1][1] + sc[1][2] + sc[1][3] + b_beta[1];
}

// ------------------------------- big GEMM ----------------------------------
// C1[m][n] = obs[m] . W_f[n][:4096] + b_f[n]   (M=32768, N=256, K=4096), row-major out
struct __attribute__((packed, aligned(4))) F4 { float x, y, z, w; };

__global__ __launch_bounds__(256) void gemm1_k(const float* __restrict__ A,
                                               const float* __restrict__ W,
                                               const float* __restrict__ bias,
                                               float* __restrict__ C1) {
  __shared__ __align__(16) float As[32][68];
  __shared__ __align__(16) float Bs[32][68];
  int bid = blockIdx.x;
  int mt = bid & 511, nt = bid >> 9;
  int m0 = mt * 64, n0 = nt * 64;
  int tid = threadIdx.x;
  int tm = tid & 15, tn = tid >> 4;
  int lr = tid >> 2;
  int lc = (tid & 3) * 8;
  float acc[4][4] = {};
  for (int k0 = 0; k0 < CONV; k0 += 32) {
    F4 a0 = *(const F4*)(A + (size_t)(m0 + lr) * CONV + k0 + lc);
    F4 a1 = *(const F4*)(A + (size_t)(m0 + lr) * CONV + k0 + lc + 4);
    F4 b0 = *(const F4*)(W + (size_t)(n0 + lr) * LDWF + k0 + lc);
    F4 b1 = *(const F4*)(W + (size_t)(n0 + lr) * LDWF + k0 + lc + 4);
    __syncthreads();
    As[lc + 0][lr] = a0.x; As[lc + 1][lr] = a0.y; As[lc + 2][lr] = a0.z; As[lc + 3][lr] = a0.w;
    As[lc + 4][lr] = a1.x; As[lc + 5][lr] = a1.y; As[lc + 6][lr] = a1.z; As[lc + 7][lr] = a1.w;
    Bs[lc + 0][lr] = b0.x; Bs[lc + 1][lr] = b0.y; Bs[lc + 2][lr] = b0.z; Bs[lc + 3][lr] = b0.w;
    Bs[lc + 4][lr] = b1.x; Bs[lc + 5][lr] = b1.y; Bs[lc + 6][lr] = b1.z; Bs[lc + 7][lr] = b1.w;
    __syncthreads();
#pragma unroll
    for (int kk = 0; kk < 32; ++kk) {
      const float4 av = *(const float4*)&As[kk][tm * 4];
      const float4 bv = *(const float4*)&Bs[kk][tn * 4];
      acc[0][0] = fmaf(av.x, bv.x, acc[0][0]); acc[0][1] = fmaf(av.x, bv.y, acc[0][1]);
      acc[0][2] = fmaf(av.x, bv.z, acc[0][2]); acc[0][3] = fmaf(av.x, bv.w, acc[0][3]);
      acc[1][0] = fmaf(av.y, bv.x, acc[1][0]); acc[1][1] = fmaf(av.y, bv.y, acc[1][1]);
      acc[1][2] = fmaf(av.y, bv.z, acc[1][2]); acc[1][3] = fmaf(av.y, bv.w, acc[1][3]);
      acc[2][0] = fmaf(av.z, bv.x, acc[2][0]); acc[2][1] = fmaf(av.z, bv.y, acc[2][1]);
      acc[2][2] = fmaf(av.z, bv.z, acc[2][2]); acc[2][3] = fmaf(av.z, bv.w, acc[2][3]);
      acc[3][0] = fmaf(av.w, bv.x, acc[3][0]); acc[3][1] = fmaf(av.w, bv.y, acc[3][1]);
      acc[3][2] = fmaf(av.w, bv.z, acc[3][2]); acc[3][3] = fmaf(av.w, bv.w, acc[3][3]);
    }
  }
  const int mrow = m0 + tm * 4;
  const int ncol = n0 + tn * 4;
  float4 bv4 = *(const float4*)(bias + ncol);
#pragma unroll
  for (int i = 0; i < 4; ++i) {
    float4 v;
    v.x = acc[i][0] + bv4.x; v.y = acc[i][1] + bv4.y;
    v.z = acc[i][2] + bv4.z; v.w = acc[i][3] + bv4.w;
    *(float4*)(C1 + (size_t)(mrow + i) * 256 + ncol) = v;
  }
}

// ------------------------------ sequential ---------------------------------
// One block per batch row. No grid sync. State in LDS; streams hit L2.
__global__ __launch_bounds__(256, 1) void seq_k(
    const float* __restrict__ hx0, const float* __restrict__ task,
    const float* __restrict__ WfT, const float* __restrict__ WihT,
    const float* __restrict__ WhhT, const float* __restrict__ b_ih,
    const float* __restrict__ b_hh, const float* __restrict__ W_u,
    const float* __restrict__ b_u, const float* __restrict__ W_s,
    const float* __restrict__ b_s, const float* __restrict__ b_pi,
    const float* __restrict__ W_beta, const float* __restrict__ C1,
    const float* __restrict__ bxv, const float* __restrict__ wpiT,
    const float* __restrict__ ggum, const float* __restrict__ bgum,
    float* __restrict__ out) {
  const int b = blockIdx.x;
  const int tid = threadIdx.x;

  __shared__ float h_sh[256], s_sh[256], M_sh[512];
  __shared__ float p_sh[16], pn_sh[16], r_sh[32], g_sh[32];
  __shared__ float red4[4][4];
  __shared__ float red16[4][16];
  __shared__ float logit_sh[16];
  __shared__ float l_sh[3];
  __shared__ float c_sh, b_sh;
  __shared__ int gidx_sh;
  __shared__ float misc_sh[3];  // 0: lp_g, 1: b', 2: lp_total

  // ---- init state from hx0 / task ----
  h_sh[tid] = hx0[b * TOT + 48 + tid];
  if (tid < 16) p_sh[tid] = hx0[b * TOT + tid];
  if (tid < 32) {
    r_sh[tid] = hx0[b * TOT + 16 + tid];
    g_sh[tid] = hx0[b * TOT + 304 + tid];
  }
  if (tid == 0) b_sh = hx0[b * TOT + 336];
  M_sh[tid]       = task[(size_t)b * 512 + tid];
  M_sh[256 + tid] = task[(size_t)b * 512 + 256 + tid];

  // per-thread persistent constants
  const float bih_r = b_ih[tid], bih_z = b_ih[256 + tid], bih_n = b_ih[512 + tid];
  const float bhh_r = b_hh[tid], bhh_z = b_hh[256 + tid], bhh_n = b_hh[512 + tid];
  const float wu_s = W_u[tid], wu_h = W_u[256 + tid];
  const float ws0 = W_s[tid], ws1 = W_s[256 + tid], ws2 = W_s[512 + tid];
  const float bu0 = b_u[0], bs0 = b_s[0], bs1 = b_s[1], bs2 = b_s[2];
  __syncthreads();

  for (int t = 0; t < T_STEPS; ++t) {
    // ---- Phase 1: s[o] = C1 row + W_f tail over [r, g, b] ----
    float sacc = C1[((size_t)t * 256 + b) * 256 + tid];
#pragma unroll
    for (int j = 0; j < 32; ++j) sacc = fmaf(r_sh[j], WfT[j * 256 + tid], sacc);
#pragma unroll
    for (int j = 0; j < 32; ++j) sacc = fmaf(g_sh[j], WfT[(32 + j) * 256 + tid], sacc);
    sacc = fmaf(b_sh, WfT[64 * 256 + tid], sacc);
    s_sh[tid] = sacc;
    __syncthreads();

    // ---- Phase 2: fused gi/gh streams (k ascending, as in R1) ----
    float gi_r = 0.f, gi_z = 0.f, gi_n = 0.f;
    float gh_r = 0.f, gh_z = 0.f, gh_n = 0.f;
#pragma unroll 8
    for (int k = 0; k < 256; ++k) {
      const float sv = s_sh[k];
      const float hv = h_sh[k];
      const float* wi = WihT + k * 768 + tid;
      const float* wh = WhhT + k * 768 + tid;
      gi_r = fmaf(sv, wi[0],   gi_r);
      gi_z = fmaf(sv, wi[256], gi_z);
      gi_n = fmaf(sv, wi[512], gi_n);
      gh_r = fmaf(hv, wh[0],   gh_r);
      gh_z = fmaf(hv, wh[256], gh_z);
      gh_n = fmaf(hv, wh[512], gh_n);
    }
    const float hold = h_sh[tid];
    // partial reductions for c (W_u over [s,h]) and l (W_s over h)
    {
      float pc = fmaf(wu_s, sacc, wu_h * hold);
      float p0 = ws0 * hold, p1 = ws1 * hold, p2 = ws2 * hold;
      pc = waveRed(pc); p0 = waveRed(p0); p1 = waveRed(p1); p2 = waveRed(p2);
      int w = tid >> 6;
      if ((tid & 63) == 0) { red4[w][0] = pc; red4[w][1] = p0; red4[w][2] = p1; red4[w][3] = p2; }
    }
    __syncthreads();
    if (tid == 0) {
      float cs = red4[0][0] + red4[1][0] + red4[2][0] + red4[3][0] + bu0;
      c_sh = 1.0f / (1.0f + expf(-cs));
      float x0 = red4[0][1] + red4[1][1] + red4[2][1] + red4[3][1] + bs0;
      float x1 = red4[0][2] + red4[1][2] + red4[2][2] + red4[3][2] + bs1;
      float x2 = red4[0][3] + red4[1][3] + red4[2][3] + red4[3][3] + bs2;
      float m = fmaxf(x0, fmaxf(x1, x2));
      float e0 = expf(x0 - m), e1 = expf(x1 - m), e2 = expf(x2 - m);
      float es = e0 + e1 + e2;
      l_sh[0] = e0 / es; l_sh[1] = e1 / es; l_sh[2] = e2 / es;
    }
    __syncthreads();
    const float c = c_sh, omc = 1.0f - c;

    // ---- Phase 3: GRU + gated h'; p_new ----
    float hg;
    {
      float rr = 1.0f / (1.0f + expf(-(gi_r + bih_r + gh_r + bhh_r)));
      float zz = 1.0f / (1.0f + expf(-(gi_z + bih_z + gh_z + bhh_z)));
      float nn = tanhf(gi_n + bih_n + rr * (gh_n + bhh_n));
      float hnew = (1.0f - zz) * nn + zz * hold;
      hg = c * hnew + omc * hold;
      h_sh[tid] = hg;
    }
    if (tid < 16) {
      float pm1 = (tid > 0) ? p_sh[tid - 1] : 0.f;
      float pp1 = (tid < 15) ? p_sh[tid + 1] : 0.f;
      pn_sh[tid] = l_sh[0] * pm1 + l_sh[1] * p_sh[tid] + l_sh[2] * pp1;
    }
    __syncthreads();
    // r_new = p_new @ M, gated; p gated
    float rv = 0.f;
    if (tid < 32) {
      float acc = 0.f;
#pragma unroll
      for (int n2 = 0; n2 < 16; ++n2) acc = fmaf(pn_sh[n2], M_sh[n2 * 32 + tid], acc);
      rv = c * acc + omc * r_sh[tid];
      r_sh[tid] = rv;
    }
    if (tid < 16) p_sh[tid] = c * pn_sh[tid] + omc * p_sh[tid];

    // ---- Phase 4: logits_g = [h', r'] @ W_pi^T + b_pi ----
    {
      float part[16];
      const float* wrow = wpiT + tid * 16;
#pragma unroll
      for (int o = 0; o < 16; ++o) part[o] = hg * wrow[o];
      if (tid < 32) {
        const float* wrow2 = wpiT + (256 + tid) * 16;
#pragma unroll
        for (int o = 0; o < 16; ++o) part[o] = fmaf(rv, wrow2[o], part[o]);
      }
#pragma unroll
      for (int o = 0; o < 16; ++o) part[o] = waveRed(part[o]);
      int w = tid >> 6;
      if ((tid & 63) == 0) {
#pragma unroll
        for (int o = 0; o < 16; ++o) red16[w][o] = part[o];
      }
    }
    __syncthreads();
    if (tid < 16)
      logit_sh[tid] = red16[0][tid] + red16[1][tid] + red16[2][tid] + red16[3][tid] + b_pi[tid];
    __syncthreads();
    if (tid == 0) {
      const float* gg = ggum + ((size_t)t * 256 + b) * 16;
      float best = -3.402823466e+38f; int gidx = 0;
      for (int n2 = 0; n2 < 16; ++n2) {
        float v = logit_sh[n2] + gg[n2];
        if (v > best) { best = v; gidx = n2; }
      }
      float mx = logit_sh[0];
      for (int n2 = 1; n2 < 16; ++n2) mx = fmaxf(mx, logit_sh[n2]);
      float se = 0.f;
      for (int n2 = 0; n2 < 16; ++n2) se += expf(logit_sh[n2] - mx);
      misc_sh[0] = logit_sh[gidx] - mx - logf(se);
      gidx_sh = gidx;
    }
    __syncthreads();
    if (tid < 32) g_sh[tid] = c * M_sh[gidx_sh * 32 + tid] + omc * g_sh[tid];
    __syncthreads();
    if (tid == 0) {
      const float* bx2 = bxv + ((size_t)t * 256 + b) * 2;
      float lb0 = bx2[0], lb1 = bx2[1];
      for (int s2 = 0; s2 < 32; ++s2) {
        float gv = g_sh[s2];
        lb0 = fmaf(gv, W_beta[CONV + s2], lb0);
        lb1 = fmaf(gv, W_beta[LDWB + CONV + s2], lb1);
      }
      const float* bg = bgum + ((size_t)t * 256 + b) * 2;
      int bidx = ((lb1 + bg[1]) > (lb0 + bg[0])) ? 1 : 0;
      float mb = fmaxf(lb0, lb1);
      float seb = expf(lb0 - mb) + expf(lb1 - mb);
      float lpb = (bidx ? lb1 : lb0) - mb - logf(seb);
      misc_sh[1] = (float)bidx;
      misc_sh[2] = misc_sh[0] + lpb;
      b_sh = (float)bidx;
    }
    __syncthreads();
    // ---- outputs: [p16, r32, h256, g32, b1, lp1] ----
    {
      size_t base = ((size_t)t * 256 + b) * TOT;
      float v;
      if (tid < 16) v = p_sh[tid];
      else if (tid < 48) v = r_sh[tid - 16];
      else v = h_sh[tid - 48];
      out[base + tid] = v;
      if (tid < 82) {
        int s2 = tid + 256;
        float v2;
        if (s2 < 304) v2 = h_sh[s2 - 48];
        else if (s2 < 336) v2 = g_sh[s2 - 304];
        else if (s2 == 336) v2 = misc_sh[1];
        else v2 = misc_sh[2];
        out[base + s2] = v2;
      }
    }
    __syncthreads();
  }
}

// ------------------------------ host launch --------------------------------
extern "C" void kernel_launch(void* const* d_in, const int* in_sizes, int n_in,
                              void* d_out, int out_size, void* d_ws, size_t ws_size,
                              hipStream_t stream) {
  const float* obs    = (const float*)d_in[0];
  const float* task   = (const float*)d_in[1];
  const float* hx0    = (const float*)d_in[2];
  const float* W_ih   = (const float*)d_in[3];
  const float* W_hh   = (const float*)d_in[4];
  const float* b_ih   = (const float*)d_in[5];
  const float* b_hh   = (const float*)d_in[6];
  const float* W_f    = (const float*)d_in[7];
  const float* b_f    = (const float*)d_in[8];
  const float* W_u    = (const float*)d_in[9];
  const float* b_u    = (const float*)d_in[10];
  const float* W_s    = (const float*)d_in[11];
  const float* b_s    = (const float*)d_in[12];
  const float* W_pi   = (const float*)d_in[13];
  const float* b_pi   = (const float*)d_in[14];
  const float* W_beta = (const float*)d_in[15];
  const float* b_beta = (const float*)d_in[16];

  char* ws = (char*)d_ws;
  size_t off = 0;
  auto take = [&](size_t bytes) {
    size_t r = off;
    off += (bytes + 255) & ~(size_t)255;
    return r;
  };
  size_t off_wpiT = take((size_t)288 * 16 * 4);
  size_t off_WihT = take((size_t)768 * 256 * 4);
  size_t off_WhhT = take((size_t)768 * 256 * 4);
  size_t off_WfT  = take((size_t)65 * 256 * 4);
  size_t off_ggum = take((size_t)T_STEPS * B_ROWS * 16 * 4);
  size_t off_bgum = take((size_t)T_STEPS * B_ROWS * 2 * 4);
  size_t off_bx   = take((size_t)T_STEPS * B_ROWS * 2 * 4);
  size_t off_C1   = take((size_t)T_STEPS * B_ROWS * 256 * 4);
  if (off > ws_size) return;

  float* wpiT = (float*)(ws + off_wpiT);
  float* WihT = (float*)(ws + off_WihT);
  float* WhhT = (float*)(ws + off_WhhT);
  float* WfT  = (float*)(ws + off_WfT);
  float* ggum = (float*)(ws + off_ggum);
  float* bgum = (float*)(ws + off_bgum);
  float* bxv  = (float*)(ws + off_bx);
  float* C1   = (float*)(ws + off_C1);

  hipLaunchKernelGGL(prep_k, dim3(851), dim3(256), 0, stream, W_ih, W_hh, W_f, W_pi,
                     WihT, WhhT, WfT, wpiT);
  hipLaunchKernelGGL(rng_k, dim3(2304), dim3(256), 0, stream, ggum, bgum);
  hipLaunchKernelGGL(gemm1_k, dim3(2048), dim3(256), 0, stream, obs, W_f, b_f, C1);
  hipLaunchKernelGGL(bx_k, dim3(32768), dim3(256), 0, stream, obs, W_beta, b_beta, bxv);
  hipLaunchKernelGGL(seq_k, dim3(256), dim3(256), 0, stream,
                     hx0, task, WfT, WihT, WhhT, b_ih, b_hh, W_u, b_u, W_s, b_s, b_pi,
                     W_beta, C1, bxv, wpiT, ggum, bgum, (float*)d_out);
}